// Round 6
// baseline (187.126 us; speedup 1.0000x reference)
//
#include <hip/hip_runtime.h>
#include <math.h>

// CIRNet single-kernel with ticket-ordered decoupled lookback:
// T=1048576 rows x 18 feats -> r_predicts/regs/dts.
// 1024 blocks x 256 threads (4 waves, 38.9KB LDS -> 4 blocks/CU, 16 waves/CU — R4's
// best-measured staging geometry). Each block takes a ticket (atomic; ticket order ==
// start order -> a block only waits on already-running blocks: deadlock-free, no
// co-residency assumption), stages its 256 quads via per-wave LDS transpose
// (coalesced global_load_lds, wave-local waits), computes coeffs + regs/dts + GSTEP
// affine maps + block scan ALL in registers, publishes its aggregate (release flag),
// then wave 0 composes the full predecessor product in 64-wide windows using RELAXED
// agent-scope atomic loads (L2-direct, no per-poll L1-invalidate) and the block
// replays + stores. No dc/pref HBM round-trip, no second kernel.
// All FP dot/step math identical to the validated kernels.
#define NSTEPS   1048575
#define FEAT     18
#define NBLK     1024                // blocks (tickets)
#define NT       256                 // threads per block (4 waves)
#define NQ       (NBLK * NT)         // 262144 quads x 4 rows = 1048576 rows
#define SLOTS    608                 // 19 * 32 float4 slots per half-wave pass
#define WBYTES   (SLOTS * 16)        // 9728 B per-wave stage buffer

#define GLDS16(g, l) \
    __builtin_amdgcn_global_load_lds((const __attribute__((address_space(1))) void*)(g), \
                                     (__attribute__((address_space(3))) void*)(l), 16, 0, 0)

#define WAIT_VM0()   asm volatile("s_waitcnt vmcnt(0)" ::: "memory")
#define WAIT_LGKM0() asm volatile("s_waitcnt lgkmcnt(0)" ::: "memory")

// one step + derivative-product update (identical math to validated kernel)
#define GSTEP(dd, cc) { \
    float a   = fmaf(-k, (dd), 1.f); \
    float b   = kth * (dd); \
    float ar  = fabsf(r); \
    float sq  = sqrtf(ar); \
    float inv = (ar > 1e-30f) ? rsqrtf(ar) : 0.f; \
    float g   = fmaf(0.5f * (cc), copysignf(inv, r), a); \
    r = fmaf((cc), sq, fmaf(a, r, b)); \
    P *= g; }

#define FSTEP(dd, cc) { \
    float a = fmaf(-k, (dd), 1.f); \
    float b = kth * (dd); \
    rr = fmaf((cc), sqrtf(fabsf(rr)), fmaf(a, rr, b)); }

// sig & eps dot-products, same fma order as validated kernel
#define DOTSE(S0,S1,S2,S3,S4,S5,S6,S7, E0,E1,E2,E3,E4,E5,E6,E7, sigv, epv) { \
    float sig_ = sb0; \
    sig_ = fmaf((S0), sw0, sig_); sig_ = fmaf((S1), sw1, sig_); \
    sig_ = fmaf((S2), sw2, sig_); sig_ = fmaf((S3), sw3, sig_); \
    sig_ = fmaf((S4), sw4, sig_); sig_ = fmaf((S5), sw5, sig_); \
    sig_ = fmaf((S6), sw6, sig_); sig_ = fmaf((S7), sw7, sig_); \
    float ep_ = 0.f; \
    ep_ = fmaf((E0), ew0, ep_); ep_ = fmaf((E1), ew1, ep_); \
    ep_ = fmaf((E2), ew2, ep_); ep_ = fmaf((E3), ew3, ep_); \
    ep_ = fmaf((E4), ew4, ep_); ep_ = fmaf((E5), ew5, ep_); \
    ep_ = fmaf((E6), ew6, ep_); ep_ = fmaf((E7), ew7, ep_); \
    (sigv) = sig_; (epv) = ep_; }

// read one padded quad (18 float4 at stride-19 slots) and compute coefficients
#define EXTRACT_COMPUTE(JROW) { \
    const float4* sr = (const float4*)lw + 19 * (JROW); \
    float4 u0 = sr[0],  u1  = sr[1],  u2  = sr[2],  u3  = sr[3],  u4  = sr[4]; \
    float4 u5 = sr[5],  u6  = sr[6],  u7  = sr[7],  u8  = sr[8]; \
    float4 u9 = sr[9],  u10 = sr[10], u11 = sr[11], u12 = sr[12], u13 = sr[13]; \
    float4 u14 = sr[14], u15 = sr[15], u16 = sr[16], u17 = sr[17]; \
    tfirst = u0.x; t3 = u13.z; \
    d0 = u4.z  - u0.x;  d1 = u9.x - u4.z;  d2 = u13.z - u9.x; \
    float ep0, ep1, ep2; \
    DOTSE(u0.z,u0.w,u1.x,u1.y,u1.z,u1.w,u2.x,u2.y, \
          u2.z,u2.w,u3.x,u3.y,u3.z,u3.w,u4.x,u4.y, sig0, ep0) \
    DOTSE(u5.x,u5.y,u5.z,u5.w,u6.x,u6.y,u6.z,u6.w, \
          u7.x,u7.y,u7.z,u7.w,u8.x,u8.y,u8.z,u8.w, sig1, ep1) \
    DOTSE(u9.z,u9.w,u10.x,u10.y,u10.z,u10.w,u11.x,u11.y, \
          u11.z,u11.w,u12.x,u12.y,u12.z,u12.w,u13.x,u13.y, sig2, ep2) \
    DOTSE(u14.x,u14.y,u14.z,u14.w,u15.x,u15.y,u15.z,u15.w, \
          u16.x,u16.y,u16.z,u16.w,u17.x,u17.y,u17.z,u17.w, sig3, ep3) \
    c0v = sig0 * ep0 * sqrtf(fabsf(d0)); \
    c1v = sig1 * ep1 * sqrtf(fabsf(d1)); \
    c2v = sig2 * ep2 * sqrtf(fabsf(d2)); }

__device__ __forceinline__ void stage_pass(const float4* __restrict__ base4,
                                           char* lds_buf, int lane)
{
    int jr = lane / 19;                 // quad within pass
    int ic = lane - 19 * jr;            // padded col
#pragma unroll
    for (int i = 0; i < 10; ++i) {
        int col = (ic == 18) ? 17 : ic; // pad slot -> duplicate col 17 (in-bounds)
        const float4* src = base4 + (18 * jr + col);
        if (i < 9) {
            GLDS16(src, lds_buf + i * 1024);
        } else if (lane < 32) {         // partial tail: slots 576..607 (exec-masked)
            GLDS16(src, lds_buf + 9 * 1024);
        }
        jr += 3; ic += 7;               // advance slot by 64 = 3*19 + 7
        if (ic >= 19) { ic -= 19; ++jr; }
    }
}

__device__ __forceinline__ void wave_scan_affine(float& A, float& B, int lane) {
#pragma unroll
    for (int d = 1; d < 64; d <<= 1) {
        float pA = __shfl_up(A, d, 64);
        float pB = __shfl_up(B, d, 64);
        if (lane >= d) { B = fmaf(A, pB, B); A *= pA; }
    }
}

__global__ void __launch_bounds__(NT) cir_one(
    const float* __restrict__ trace,
    const float* __restrict__ sW, const float* __restrict__ sb,
    const float* __restrict__ eW, const float* __restrict__ kp,
    const float* __restrict__ thp,
    float* __restrict__ out,
    int* __restrict__ flags, unsigned int* __restrict__ ticket,
    float* __restrict__ stA, float* __restrict__ stB)
{
    __shared__ __align__(16) char stage[4 * WBYTES];        // 38912 B -> 4 blocks/CU
    __shared__ float wAs[4], wBs[4];
    __shared__ float bePair[2];
    __shared__ int vbS;

    const int tid = threadIdx.x, lane = tid & 63, wid = tid >> 6;

    if (tid == 0)
        vbS = (int)__hip_atomic_fetch_add(ticket, 1u, __ATOMIC_RELAXED,
                                          __HIP_MEMORY_SCOPE_AGENT);
    __syncthreads();
    const int vb = vbS;                                     // virtual (ticket) block id
    const long c = (long)vb * NT + tid;                     // thread's quad index
    char* lw = stage + wid * WBYTES;                        // per-wave private buffer
    const float4* t4 = (const float4*)trace;
    const long waveQuad = (long)vb * NT + (long)wid * 64;

    stage_pass(t4 + waveQuad * 18, lw, lane);               // pass 0: lanes 0..31's quads

    const float k = kp[0], th = thp[0], kth = k * th, tkth2 = 2.f * kth;
    const float sb0 = sb[0];
    const float sw0 = sW[0], sw1 = sW[1], sw2 = sW[2], sw3 = sW[3];
    const float sw4 = sW[4], sw5 = sW[5], sw6 = sW[6], sw7 = sW[7];
    const float ew0 = eW[0], ew1 = eW[1], ew2 = eW[2], ew3 = eW[3];
    const float ew4 = eW[4], ew5 = eW[5], ew6 = eW[6], ew7 = eW[7];
    const float t0g = trace[0], r0v = trace[1];

    float tfirst, t3, d0, d1, d2, c0v, c1v, c2v, sig0, sig1, sig2, sig3, ep3;

    WAIT_VM0();                         // pass-0 data in LDS (wave-local wait)
    if (lane < 32) EXTRACT_COMPUTE(lane)
    WAIT_LGKM0();                       // extraction reads done before overwrite

    stage_pass(t4 + (waveQuad + 32) * 18, lw, lane);        // pass 1: lanes 32..63
    WAIT_VM0();
    if (lane >= 32) EXTRACT_COMPUTE(lane - 32)

    // t of next quad's first row: cross-half shuffle; lane 63 loads (1 txn/wave)
    float tnext = __shfl_down(tfirst, 1, 64);
    if (lane == 63)
        tnext = (c + 1 < (long)NQ) ? trace[(c * 4 + 4) * FEAT] : 0.f;
    float d3 = tnext - t3;
    const long n0 = c * 4;
    float c3v = sig3 * ep3 * sqrtf(fabsf(d3));
    if (n0 + 4 > NSTEPS) { d3 = 0.f; c3v = 0.f; }           // step NSTEPS is pad

    // regs/dts stores (issued early; overlap with scan/lookback)
    out[NSTEPS + n0 + 0] = fmaf(-sig0, sig0, tkth2);
    out[NSTEPS + n0 + 1] = fmaf(-sig1, sig1, tkth2);
    out[NSTEPS + n0 + 2] = fmaf(-sig2, sig2, tkth2);
    out[2L * NSTEPS + n0 + 0] = d0;
    out[2L * NSTEPS + n0 + 1] = d1;
    out[2L * NSTEPS + n0 + 2] = d2;
    if (n0 + 4 <= NSTEPS) {
        out[NSTEPS + n0 + 3] = fmaf(-sig3, sig3, tkth2);
        out[2L * NSTEPS + n0 + 3] = d3;
    }

    // affine map for this quad: r -> A*r + B (seed + 4 Newton-linearized steps)
    float s = th + (r0v - th) * __expf(-k * (tfirst - t0g));
    float r = s, P = 1.f;
    GSTEP(d0, c0v)
    GSTEP(d1, c1v)
    GSTEP(d2, c2v)
    GSTEP(d3, c3v)
    float A = P, Bv = fmaf(-P, s, r);

    // block scan over 256 thread maps (4 waves)
    float iA = A, iB = Bv;
    wave_scan_affine(iA, iB, lane);
    if (lane == 63) { wAs[wid] = iA; wBs[wid] = iB; }
    __syncthreads();
    if (wid == 0) {
        float aA = (lane < 4) ? wAs[lane] : 1.f;
        float aB = (lane < 4) ? wBs[lane] : 0.f;
        wave_scan_affine(aA, aB, lane);
        if (lane < 4) { wAs[lane] = aA; wBs[lane] = aB; }
    }
    __syncthreads();
    float weA = 1.f, weB = 0.f;
    if (wid > 0) { weA = wAs[wid - 1]; weB = wBs[wid - 1]; }
    float eA = __shfl_up(iA, 1, 64), eB = __shfl_up(iB, 1, 64);
    if (lane == 0) { eA = 1.f; eB = 0.f; }
    float Ate = eA * weA;                 // thread-exclusive prefix within block
    float Bte = fmaf(eA, weB, eB);

    // publish this block's aggregate: values relaxed (L2-direct), flag release
    if (tid == 0) {
        __hip_atomic_store(&stA[vb], wAs[3], __ATOMIC_RELAXED, __HIP_MEMORY_SCOPE_AGENT);
        __hip_atomic_store(&stB[vb], wBs[3], __ATOMIC_RELAXED, __HIP_MEMORY_SCOPE_AGENT);
        __hip_atomic_store(&flags[vb], 1, __ATOMIC_RELEASE, __HIP_MEMORY_SCOPE_AGENT);
    }

    // decoupled lookback by wave 0: full predecessor product, 64-wide windows,
    // RELAXED agent atomic loads (sc0 -> L2-direct; no per-poll L1 invalidate).
    if (wid == 0) {
        float gA = 1.f, gB = 0.f;         // product of all predecessors (oldest first)
        const int nw = (vb + 63) >> 6;
        for (int w = 0; w < nw; ++w) {
            int idx = vb - 64 * (w + 1) + lane;   // lane ascending == older -> newer
            float aA = 1.f, aB = 0.f;
            if (idx >= 0) {
                while (__hip_atomic_load(&flags[idx], __ATOMIC_RELAXED,
                                         __HIP_MEMORY_SCOPE_AGENT) == 0)
                    __builtin_amdgcn_s_sleep(1);
                aA = __hip_atomic_load(&stA[idx], __ATOMIC_RELAXED,
                                       __HIP_MEMORY_SCOPE_AGENT);
                aB = __hip_atomic_load(&stB[idx], __ATOMIC_RELAXED,
                                       __HIP_MEMORY_SCOPE_AGENT);
            }
            wave_scan_affine(aA, aB, lane);       // inclusive; lane 63 = window product
            float wA_ = __shfl(aA, 63, 64), wB_ = __shfl(aB, 63, 64);
            gB = fmaf(gA, wB_, gB);               // g = g  (newer)  o  W (older)
            gA *= wA_;
        }
        if (lane == 0) { bePair[0] = gA; bePair[1] = gB; }
    }
    __syncthreads();
    const float beA = bePair[0], beB = bePair[1];

    // corrected start for this thread's 4 steps, replay from registers, store
    float FA = Ate * beA;
    float FB = fmaf(Ate, beB, Bte);
    float rr = fmaf(FA, r0v, FB);
    float4 ov;
    FSTEP(d0, c0v) ov.x = rr;
    FSTEP(d1, c1v) ov.y = rr;
    FSTEP(d2, c2v) ov.z = rr;
    FSTEP(d3, c3v) ov.w = rr;
    long nb = 4 * c;
    if (nb + 4 <= NSTEPS) {
        *(float4*)(out + nb) = ov;
    } else {                        // last thread only (step NSTEPS is pad)
        out[nb + 0] = ov.x;
        out[nb + 1] = ov.y;
        out[nb + 2] = ov.z;
    }
}

extern "C" void kernel_launch(void* const* d_in, const int* in_sizes, int n_in,
                              void* d_out, int out_size, void* d_ws, size_t ws_size,
                              hipStream_t stream)
{
    const float* trace = (const float*)d_in[0];
    const float* sW    = (const float*)d_in[1];
    const float* sb    = (const float*)d_in[2];
    const float* eW    = (const float*)d_in[3];
    const float* kp    = (const float*)d_in[4];
    const float* thp   = (const float*)d_in[5];
    float* out = (float*)d_out;

    int*          flags  = (int*)d_ws;                    // NBLK ints
    unsigned int* ticket = (unsigned int*)(flags + NBLK); // 1 uint
    float*        stA    = (float*)(ticket + 1);          // NBLK floats
    float*        stB    = stA + NBLK;                    // NBLK floats

    // zero flags + ticket (workspace is re-poisoned before every launch)
    hipMemsetAsync(flags, 0, (NBLK + 1) * sizeof(int), stream);
    cir_one<<<NBLK, NT, 0, stream>>>(trace, sW, sb, eW, kp, thp, out,
                                     flags, ticket, stA, stB);
}

// Round 7
// 120.542 us; speedup vs baseline: 1.5524x; 1.5524x over previous
//
#include <hip/hip_runtime.h>
#include <math.h>

// CIRNet, barrier-free 2-kernel split (R4 structure, validated 124.2us) with the dc
// round-trip halved: prep stores only the c-coefficients (float4/quad); final reads
// the d-coefficients from the dts section of `out` that prep already wrote (same
// 1024-block grid -> same block->XCD mapping -> L2-hot, like dc was). Saves 4MB write
// + 4MB read. Everything else identical to R4:
//  - prep: per-wave LDS-transpose staging (coalesced global_load_lds, wave-local
//    s_waitcnt only), coeffs + regs/dts + c4 + GSTEP affine maps + block scan,
//    writes thread-exclusive prefix + block aggregate.
//  - final: barrier-free redundant scan of the 1024 aggregates, replay, store.
// All FP math order identical to the validated kernels.
#define NSTEPS   1048575
#define FEAT     18
#define NB1      1024                // prep/final blocks
#define NT1      256                 // threads per block (4 waves)
#define NQ       (NB1 * NT1)         // 262144 quads x 4 rows = 1048576 rows
#define SLOTS    608                 // 19 * 32 float4 slots per half-wave pass
#define WBYTES   (SLOTS * 16)        // 9728 B per-wave stage buffer

#define GLDS16(g, l) \
    __builtin_amdgcn_global_load_lds((const __attribute__((address_space(1))) void*)(g), \
                                     (__attribute__((address_space(3))) void*)(l), 16, 0, 0)

#define WAIT_VM0()   asm volatile("s_waitcnt vmcnt(0)" ::: "memory")
#define WAIT_LGKM0() asm volatile("s_waitcnt lgkmcnt(0)" ::: "memory")

// one step + derivative-product update (identical math to validated kernel)
#define GSTEP(dd, cc) { \
    float a   = fmaf(-k, (dd), 1.f); \
    float b   = kth * (dd); \
    float ar  = fabsf(r); \
    float sq  = sqrtf(ar); \
    float inv = (ar > 1e-30f) ? rsqrtf(ar) : 0.f; \
    float g   = fmaf(0.5f * (cc), copysignf(inv, r), a); \
    r = fmaf((cc), sq, fmaf(a, r, b)); \
    P *= g; }

#define FSTEP(dd, cc) { \
    float a = fmaf(-k, (dd), 1.f); \
    float b = kth * (dd); \
    rr = fmaf((cc), sqrtf(fabsf(rr)), fmaf(a, rr, b)); }

// sig & eps dot-products, same fma order as validated kernel
#define DOTSE(S0,S1,S2,S3,S4,S5,S6,S7, E0,E1,E2,E3,E4,E5,E6,E7, sigv, epv) { \
    float sig_ = sb0; \
    sig_ = fmaf((S0), sw0, sig_); sig_ = fmaf((S1), sw1, sig_); \
    sig_ = fmaf((S2), sw2, sig_); sig_ = fmaf((S3), sw3, sig_); \
    sig_ = fmaf((S4), sw4, sig_); sig_ = fmaf((S5), sw5, sig_); \
    sig_ = fmaf((S6), sw6, sig_); sig_ = fmaf((S7), sw7, sig_); \
    float ep_ = 0.f; \
    ep_ = fmaf((E0), ew0, ep_); ep_ = fmaf((E1), ew1, ep_); \
    ep_ = fmaf((E2), ew2, ep_); ep_ = fmaf((E3), ew3, ep_); \
    ep_ = fmaf((E4), ew4, ep_); ep_ = fmaf((E5), ew5, ep_); \
    ep_ = fmaf((E6), ew6, ep_); ep_ = fmaf((E7), ew7, ep_); \
    (sigv) = sig_; (epv) = ep_; }

// read one padded quad (18 float4 at stride-19 slots) and reduce to live scalars
#define EXTRACT_COMPUTE(JROW) { \
    const float4* sr = (const float4*)lw + 19 * (JROW); \
    float4 u0 = sr[0],  u1  = sr[1],  u2  = sr[2],  u3  = sr[3],  u4  = sr[4]; \
    float4 u5 = sr[5],  u6  = sr[6],  u7  = sr[7],  u8  = sr[8]; \
    float4 u9 = sr[9],  u10 = sr[10], u11 = sr[11], u12 = sr[12], u13 = sr[13]; \
    float4 u14 = sr[14], u15 = sr[15], u16 = sr[16], u17 = sr[17]; \
    tfirst = u0.x; t3 = u13.z; \
    d0 = u4.z  - u0.x;  d1 = u9.x - u4.z;  d2 = u13.z - u9.x; \
    float ep0, ep1, ep2; \
    DOTSE(u0.z,u0.w,u1.x,u1.y,u1.z,u1.w,u2.x,u2.y, \
          u2.z,u2.w,u3.x,u3.y,u3.z,u3.w,u4.x,u4.y, sig0, ep0) \
    DOTSE(u5.x,u5.y,u5.z,u5.w,u6.x,u6.y,u6.z,u6.w, \
          u7.x,u7.y,u7.z,u7.w,u8.x,u8.y,u8.z,u8.w, sig1, ep1) \
    DOTSE(u9.z,u9.w,u10.x,u10.y,u10.z,u10.w,u11.x,u11.y, \
          u11.z,u11.w,u12.x,u12.y,u12.z,u12.w,u13.x,u13.y, sig2, ep2) \
    DOTSE(u14.x,u14.y,u14.z,u14.w,u15.x,u15.y,u15.z,u15.w, \
          u16.x,u16.y,u16.z,u16.w,u17.x,u17.y,u17.z,u17.w, sig3, ep3) \
    c0v = sig0 * ep0 * sqrtf(fabsf(d0)); \
    c1v = sig1 * ep1 * sqrtf(fabsf(d1)); \
    c2v = sig2 * ep2 * sqrtf(fabsf(d2)); }

__device__ __forceinline__ void stage_pass(const float4* __restrict__ base4,
                                           char* lds_buf, int lane)
{
    int jr = lane / 19;                 // quad within pass
    int ic = lane - 19 * jr;            // padded col
#pragma unroll
    for (int i = 0; i < 10; ++i) {
        int col = (ic == 18) ? 17 : ic; // pad slot -> duplicate col 17 (in-bounds)
        const float4* src = base4 + (18 * jr + col);
        if (i < 9) {
            GLDS16(src, lds_buf + i * 1024);
        } else if (lane < 32) {         // partial tail: slots 576..607 (exec-masked)
            GLDS16(src, lds_buf + 9 * 1024);
        }
        jr += 3; ic += 7;               // advance slot by 64 = 3*19 + 7
        if (ic >= 19) { ic -= 19; ++jr; }
    }
}

__device__ __forceinline__ void wave_scan_affine(float& A, float& B, int lane) {
#pragma unroll
    for (int d = 1; d < 64; d <<= 1) {
        float pA = __shfl_up(A, d, 64);
        float pB = __shfl_up(B, d, 64);
        if (lane >= d) { B = fmaf(A, pB, B); A *= pA; }
    }
}

// ---------------- K1: stage + coeffs + regs/dts + c4 + block scan ----------------
__global__ void __launch_bounds__(NT1) cir_prep(
    const float* __restrict__ trace,
    const float* __restrict__ sW, const float* __restrict__ sb,
    const float* __restrict__ eW, const float* __restrict__ kp,
    const float* __restrict__ thp,
    float* __restrict__ out,
    float4* __restrict__ cq, float2* __restrict__ pref, float2* __restrict__ agg)
{
    __shared__ __align__(16) char stage[4 * WBYTES];        // 38912 B -> 4 blocks/CU
    __shared__ float wAs[4], wBs[4];

    const int tid = threadIdx.x, lane = tid & 63, wid = tid >> 6, bid = blockIdx.x;
    const long c = (long)bid * NT1 + tid;                   // thread's quad index
    char* lw = stage + wid * WBYTES;                        // per-wave private buffer
    const float4* t4 = (const float4*)trace;
    const long waveQuad = (long)bid * NT1 + (long)wid * 64;

    stage_pass(t4 + waveQuad * 18, lw, lane);               // pass 0: lanes 0..31's quads

    const float k = kp[0], th = thp[0], kth = k * th, tkth2 = 2.f * kth;
    const float sb0 = sb[0];
    const float sw0 = sW[0], sw1 = sW[1], sw2 = sW[2], sw3 = sW[3];
    const float sw4 = sW[4], sw5 = sW[5], sw6 = sW[6], sw7 = sW[7];
    const float ew0 = eW[0], ew1 = eW[1], ew2 = eW[2], ew3 = eW[3];
    const float ew4 = eW[4], ew5 = eW[5], ew6 = eW[6], ew7 = eW[7];
    const float t0g = trace[0], r0v = trace[1];

    float tfirst, t3, d0, d1, d2, c0v, c1v, c2v, sig0, sig1, sig2, sig3, ep3;

    WAIT_VM0();                         // pass-0 data in LDS (wave-local wait)
    if (lane < 32) EXTRACT_COMPUTE(lane)
    WAIT_LGKM0();                       // extraction reads done before overwrite

    stage_pass(t4 + (waveQuad + 32) * 18, lw, lane);        // pass 1: lanes 32..63
    WAIT_VM0();
    if (lane >= 32) EXTRACT_COMPUTE(lane - 32)

    // t of next quad's first row: cross-half shuffle; lane 63 loads (1 txn/wave)
    float tnext = __shfl_down(tfirst, 1, 64);
    if (lane == 63)
        tnext = (c + 1 < (long)NQ) ? trace[(c * 4 + 4) * FEAT] : 0.f;
    float d3 = tnext - t3;
    const long n0 = c * 4;
    float c3v = sig3 * ep3 * sqrtf(fabsf(d3));
    if (n0 + 4 > NSTEPS) { d3 = 0.f; c3v = 0.f; }           // step NSTEPS is pad

    // regs/dts stores (dts doubles as the d-coefficient array for cir_final)
    out[NSTEPS + n0 + 0] = fmaf(-sig0, sig0, tkth2);
    out[NSTEPS + n0 + 1] = fmaf(-sig1, sig1, tkth2);
    out[NSTEPS + n0 + 2] = fmaf(-sig2, sig2, tkth2);
    out[2L * NSTEPS + n0 + 0] = d0;
    out[2L * NSTEPS + n0 + 1] = d1;
    out[2L * NSTEPS + n0 + 2] = d2;
    if (n0 + 4 <= NSTEPS) {
        out[NSTEPS + n0 + 3] = fmaf(-sig3, sig3, tkth2);
        out[2L * NSTEPS + n0 + 3] = d3;
    }

    // c-coefficients for K2's replay (d comes from dts in `out`)
    cq[c] = make_float4(c0v, c1v, c2v, c3v);

    // affine map for this quad: r -> A*r + B (seed + 4 Newton-linearized steps)
    float s = th + (r0v - th) * __expf(-k * (tfirst - t0g));
    float r = s, P = 1.f;
    GSTEP(d0, c0v)
    GSTEP(d1, c1v)
    GSTEP(d2, c2v)
    GSTEP(d3, c3v)
    float A = P, Bv = fmaf(-P, s, r);

    // block scan over 256 thread maps (4 waves)
    float iA = A, iB = Bv;
    wave_scan_affine(iA, iB, lane);
    if (lane == 63) { wAs[wid] = iA; wBs[wid] = iB; }
    __syncthreads();
    if (wid == 0) {
        float aA = (lane < 4) ? wAs[lane] : 1.f;
        float aB = (lane < 4) ? wBs[lane] : 0.f;
        wave_scan_affine(aA, aB, lane);
        if (lane < 4) { wAs[lane] = aA; wBs[lane] = aB; }
    }
    __syncthreads();
    float weA = 1.f, weB = 0.f;
    if (wid > 0) { weA = wAs[wid - 1]; weB = wBs[wid - 1]; }
    float eA = __shfl_up(iA, 1, 64), eB = __shfl_up(iB, 1, 64);
    if (lane == 0) { eA = 1.f; eB = 0.f; }

    pref[c] = make_float2(eA * weA, fmaf(eA, weB, eB));     // thread-exclusive prefix
    if (tid == 0) agg[bid] = make_float2(wAs[3], wBs[3]);   // block aggregate
}

// ---------------- K2: barrier-free global scan + replay ----------------
__global__ void __launch_bounds__(NT1) cir_final(
    const float* __restrict__ trace,
    const float* __restrict__ kp, const float* __restrict__ thp,
    const float4* __restrict__ cq, const float2* __restrict__ pref,
    const float2* __restrict__ agg,
    float* __restrict__ out)
{
    __shared__ float2 incs[NB1];        // 8 KB inclusive scan of block aggregates
    __shared__ float wA2[4], wB2[4];

    const int tid = threadIdx.x, lane = tid & 63, wid = tid >> 6, bid = blockIdx.x;
    const long c = (long)bid * NT1 + tid;
    const float k = kp[0], th = thp[0], kth = k * th;
    const float r0v = trace[1];

    // every block scans all 1024 aggregates (ordered): 4 sequential per thread
    float2 a0 = agg[4 * tid + 0], a1 = agg[4 * tid + 1];
    float2 a2 = agg[4 * tid + 2], a3 = agg[4 * tid + 3];
    float cA = a0.x, cB = a0.y;                       // compose in order (earlier first)
    cB = fmaf(a1.x, cB, a1.y); cA *= a1.x;
    cB = fmaf(a2.x, cB, a2.y); cA *= a2.x;
    cB = fmaf(a3.x, cB, a3.y); cA *= a3.x;

    float iA = cA, iB = cB;                           // inclusive over thread-chunks
    wave_scan_affine(iA, iB, lane);
    if (lane == 63) { wA2[wid] = iA; wB2[wid] = iB; }
    __syncthreads();
    if (wid == 0) {
        float aA = (lane < 4) ? wA2[lane] : 1.f;
        float aB = (lane < 4) ? wB2[lane] : 0.f;
        wave_scan_affine(aA, aB, lane);
        if (lane < 4) { wA2[lane] = aA; wB2[lane] = aB; }
    }
    __syncthreads();
    float weA = 1.f, weB = 0.f;
    if (wid > 0) { weA = wA2[wid - 1]; weB = wB2[wid - 1]; }
    float eA = __shfl_up(iA, 1, 64), eB = __shfl_up(iB, 1, 64);
    if (lane == 0) { eA = 1.f; eB = 0.f; }
    float EA = eA * weA, EB = fmaf(eA, weB, eB);      // exclusive prefix of chunk 4*tid

    // inclusive values for this thread's 4 aggregates -> LDS
    float xA = a0.x * EA,  xB = fmaf(a0.x, EB, a0.y);
    incs[4 * tid + 0] = make_float2(xA, xB);
    xB = fmaf(a1.x, xB, a1.y); xA *= a1.x;
    incs[4 * tid + 1] = make_float2(xA, xB);
    xB = fmaf(a2.x, xB, a2.y); xA *= a2.x;
    incs[4 * tid + 2] = make_float2(xA, xB);
    xB = fmaf(a3.x, xB, a3.y); xA *= a3.x;
    incs[4 * tid + 3] = make_float2(xA, xB);
    __syncthreads();

    float beA = 1.f, beB = 0.f;
    if (bid > 0) { float2 p = incs[bid - 1]; beA = p.x; beB = p.y; }

    // replay this thread's 4 steps from the corrected start.
    // c-coeffs from cq; d-coeffs from the dts section of out (written by cir_prep,
    // same block->XCD mapping -> L2-hot). Last thread guards the 1-dword OOB (pad).
    const long n0 = 4 * c;
    const float* dts = out + 2L * NSTEPS + n0;
    float4 cv = cq[c];
    float d0, d1, d2, d3;
    if (n0 + 4 <= NSTEPS) {
        float2 dA = *(const float2*)(dts);
        float2 dB = *(const float2*)(dts + 2);
        d0 = dA.x; d1 = dA.y; d2 = dB.x; d3 = dB.y;
    } else {                            // last thread: dts[n0+3] doesn't exist (pad)
        d0 = dts[0]; d1 = dts[1]; d2 = dts[2]; d3 = 0.f;
    }
    float2 pr = pref[c];
    float FA = pr.x * beA;
    float FB = fmaf(pr.x, beB, pr.y);
    float rr = fmaf(FA, r0v, FB);
    float4 ov;
    FSTEP(d0, cv.x) ov.x = rr;
    FSTEP(d1, cv.y) ov.y = rr;
    FSTEP(d2, cv.z) ov.z = rr;
    FSTEP(d3, cv.w) ov.w = rr;
    if (n0 + 4 <= NSTEPS) {
        *(float4*)(out + n0) = ov;
    } else {                        // last thread only (step NSTEPS is pad)
        out[n0 + 0] = ov.x;
        out[n0 + 1] = ov.y;
        out[n0 + 2] = ov.z;
    }
}

extern "C" void kernel_launch(void* const* d_in, const int* in_sizes, int n_in,
                              void* d_out, int out_size, void* d_ws, size_t ws_size,
                              hipStream_t stream)
{
    const float* trace = (const float*)d_in[0];
    const float* sW    = (const float*)d_in[1];
    const float* sb    = (const float*)d_in[2];
    const float* eW    = (const float*)d_in[3];
    const float* kp    = (const float*)d_in[4];
    const float* thp   = (const float*)d_in[5];
    float* out = (float*)d_out;

    float4* cq   = (float4*)d_ws;           // NQ float4 = 4 MB
    float2* pref = (float2*)(cq + NQ);      // NQ float2 = 2 MB
    float2* agg  = pref + NQ;               // NB1 float2 = 8 KB

    cir_prep<<<NB1, NT1, 0, stream>>>(trace, sW, sb, eW, kp, thp, out, cq, pref, agg);
    cir_final<<<NB1, NT1, 0, stream>>>(trace, kp, thp, cq, pref, agg, out);
}